// Round 4
// baseline (1338.955 us; speedup 1.0000x reference)
//
#include <hip/hip_runtime.h>
#include <math.h>
#include <stdint.h>

#define BATCH 4096
#define MCAND 50
#define NTOP 32
#define HID 100
#define EPS_ROWS 98
#define EPS_BLK  (EPS_ROWS*MCAND)            /* 4900 floats per batch element */
#define WS_NEED  ((size_t)BATCH*EPS_BLK*4u)  /* 80,281,600 B */

#define MINVC  (-0x1.fffffep-1f)   /* nextafter(-1,0) */
#define SQRT2C (0x1.6a09e6p+0f)    /* fp32 sqrt(2) */

__device__ __forceinline__ uint32_t rotl32(uint32_t v, int d){ return (v<<d)|(v>>(32-d)); }

// JAX threefry2x32 core (20 rounds, 5 key injections)
__device__ __forceinline__ void tf2x32(uint32_t k0, uint32_t k1, uint32_t x0, uint32_t x1,
                                       uint32_t &o0, uint32_t &o1){
  uint32_t k2 = k0 ^ k1 ^ 0x1BD11BDAu;
  x0 += k0; x1 += k1;
#define RND(r) { x0 += x1; x1 = rotl32(x1,(r)); x1 ^= x0; }
  RND(13) RND(15) RND(26) RND(6)
  x0 += k1; x1 += k2 + 1u;
  RND(17) RND(29) RND(16) RND(24)
  x0 += k2; x1 += k0 + 2u;
  RND(13) RND(15) RND(26) RND(6)
  x0 += k0; x1 += k1 + 3u;
  RND(17) RND(29) RND(16) RND(24)
  x0 += k1; x1 += k2 + 4u;
  RND(13) RND(15) RND(26) RND(6)
  x0 += k2; x1 += k0 + 5u;
#undef RND
  o0 = x0; o1 = x1;
}

// XLA ErfInv32 (Giles). w = -log1p(-x*x)
__device__ __forceinline__ float erfinv32(float x){
  float w = -log1pf(-x*x);
  float p;
  if (w < 5.0f){
    w = w - 2.5f;
    p = 2.81022636e-08f;
    p = fmaf(p, w, 3.43273939e-07f);
    p = fmaf(p, w, -3.5233877e-06f);
    p = fmaf(p, w, -4.39150654e-06f);
    p = fmaf(p, w, 0.00021858087f);
    p = fmaf(p, w, -0.00125372503f);
    p = fmaf(p, w, -0.00417768164f);
    p = fmaf(p, w, 0.246640727f);
    p = fmaf(p, w, 1.50140941f);
  } else {
    w = sqrtf(w) - 3.0f;
    p = -0.000200214257f;
    p = fmaf(p, w, 0.000100950558f);
    p = fmaf(p, w, 0.00134934322f);
    p = fmaf(p, w, -0.00367342844f);
    p = fmaf(p, w, 0.00573950773f);
    p = fmaf(p, w, -0.0076224613f);
    p = fmaf(p, w, 0.00943887047f);
    p = fmaf(p, w, 1.00167406f);
    p = fmaf(p, w, 2.83297682f);
  }
  return p*x;
}

// ---- VALU-only lane exchanges (no DS pipe) ----
#define DPPF(v, CTRL) __int_as_float(__builtin_amdgcn_update_dpp( \
    0, __float_as_int(v), (CTRL), 0xF, 0xF, true))
#define DPPI(v, CTRL) __builtin_amdgcn_update_dpp(0, (v), (CTRL), 0xF, 0xF, true)
#define DPPADD(v, CTRL) ((v) + DPPF((v), (CTRL)))

__device__ __forceinline__ float fswap4(float v){        // v[lane^4]
  float a = DPPF(v, 0x114);   // row_shr:4
  float b = DPPF(v, 0x104);   // row_shl:4
  return (threadIdx.x & 4) ? a : b;
}
__device__ __forceinline__ int iswap4(int v){
  int a = DPPI(v, 0x114), b = DPPI(v, 0x104);
  return (threadIdx.x & 4) ? a : b;
}
__device__ __forceinline__ float fswap8(float v){        // v[lane^8] = row_ror:8
  return DPPF(v, 0x128);
}
__device__ __forceinline__ float fswap16(float v){       // v[lane^16]
#if __has_builtin(__builtin_amdgcn_permlane16_swap)
  auto r = __builtin_amdgcn_permlane16_swap(__float_as_uint(v), __float_as_uint(v), false, false);
  return __uint_as_float((threadIdx.x & 16) ? r[0] : r[1]);
#else
  return __shfl_xor(v, 16, 64);
#endif
}
__device__ __forceinline__ float fswap32(float v){       // v[lane^32]
#if __has_builtin(__builtin_amdgcn_permlane32_swap)
  auto r = __builtin_amdgcn_permlane32_swap(__float_as_uint(v), __float_as_uint(v), false, false);
  return __uint_as_float((threadIdx.x & 32) ? r[0] : r[1]);
#else
  return __shfl_xor(v, 32, 64);
#endif
}

// ---------------------------------------------------------------------------
// Piecewise-linear CEM kernel, fused RNG, latency-hidden eps staging.
//
//   h2pre[n] = T1[r][n] + a*T2[r][n],  r = #{t_k < a}  (prefix tables, fp32)
//
// Init: wave0 builds the 101x100 (T1,T2) prefix table; waves 1-7 generate the
// ENTIRE per-block eps tensor eps[t][c] (98x50, bit-identical threefry/erfinv)
// into d_ws ([b][t][c] contiguous) — this removes all in-loop RNG and the
// separate pre-kernels, and makes in-loop eps reads L2-hot.
// Loop (2 barriers):
//   G: waves 0-6 gather q(t) via float4 pair loads; wave7 every 3rd iter
//      stages 3 eps rows (3 coalesced L2 loads -> EPB[150]); the vmcnt drain
//      at B1 lands on an idle wave once per window (r3's per-iter HBM drain
//      on the stats wave was the bottleneck).
//   B1;  S: wave0 top-32 mu/std (VALU bitonic) -> A[] = a(t+1);  B2.
// LDS: T(80,800) + A(200) + QB(200) + EPB(600) = 81,800 B -> 2 blocks/CU.
// ---------------------------------------------------------------------------
template<bool EPSG>
__global__ __launch_bounds__(512, 4) void cem_kernel(
    const float* __restrict__ states, const float* __restrict__ W1,
    const float* __restrict__ b1,     const float* __restrict__ W2,
    const float* __restrict__ b2,     const float* __restrict__ W3,
    const float* __restrict__ b3,     float* __restrict__ epsg,
    float* __restrict__ out)
{
  __shared__ __align__(16) float smem[20452];           // 81,808 B
  float2* const T2D  = (float2*)smem;                   // [101][100] (T1,T2)
  int*    const ORD  = (int*)(smem + 300);              // init scratch (in T)
  float*  const ST   = smem + 400;                      // init scratch (in T)
  float*  const A    = smem + 20200;                    // [50] current angles
  float*  const QB   = smem + 20250;                    // [50] q values
  float*  const EPB  = smem + 20300;                    // [150] eps window

  const int tid  = threadIdx.x;
  const int b    = blockIdx.x;
  const int wv   = tid >> 6;
  const int lane = tid & 63;
  const int gc   = tid >> 3;            // gather candidate (8 lanes/cand)
  const int gj   = tid & 7;
  const bool gact = (tid < 8*MCAND);    // tid < 400 (waves 0-6)

  // per-thread W3 pair slice for the gather (cols n = 2p, 2p+1; p = gj+8i)
  float w3a[7], w3b[7];
#pragma unroll
  for (int i = 0; i < 7; ++i){
    int p = gj + (i<<3);
    bool valid = (p < MCAND);           // 50 float2-pairs cover 100 cols
    w3a[i] = valid ? W3[2*p]   : 0.0f;
    w3b[i] = valid ? W3[2*p+1] : 0.0f;
  }
  const float sB3v = b3[0];

  // ---------- init P0: u, v, thresholds ----------
  if (tid < HID){
    float u = fmaf(states[2*b], W1[tid], fmaf(states[2*b+1], W1[HID+tid], b1[tid]));
    float v = W1[2*HID+tid];
    float tt = (v != 0.0f) ? (-u / v) : INFINITY;
    smem[tid]     = u;
    smem[HID+tid] = v;
    smem[200+tid] = tt;
  }
  __syncthreads();

  // ---------- init P1: stable rank-by-count, scatter sorted ----------
  if (tid < HID){
    float tk = smem[200+tid];
    int rk = 0;
    for (int j2 = 0; j2 < HID; ++j2){
      float tj = smem[200+j2];
      rk += (tj < tk || (tj == tk && j2 < tid)) ? 1 : 0;
    }
    float u = smem[tid], v = smem[HID+tid];
    // neg-type: active iff a < t (v<0, or v==0 with u>0 -> always active, t=+inf)
    int neg = (v < 0.0f || (v == 0.0f && u > 0.0f)) ? 1 : 0;
    ST[rk]  = tk;
    ORD[rk] = tid | (neg << 7);
  }
  __syncthreads();

  // ---------- init P1.5: meta -> registers (wave0) + thresholds -> regs ----------
  int kpA = 0, kpB = 0; float cuA = 0.f, cvA = 0.f, cuB = 0.f, cvB = 0.f;
  if (wv == 0){
    kpA = ORD[lane];
    int kiA = kpA & 127;
    float uA = smem[kiA], vA = smem[HID+kiA];
    cuA = (kpA & 128) ? -uA : uA;     // signed delta for prefix pass
    cvA = (kpA & 128) ? -vA : vA;
    if (lane < 36){
      kpB = ORD[64+lane];
      int kiB = kpB & 127;
      float uB = smem[kiB], vB = smem[HID+kiB];
      cuB = (kpB & 128) ? -uB : uB;
      cvB = (kpB & 128) ? -vB : vB;
    }
  }
  float st_r[13];                       // loop-invariant thresholds in regs
#pragma unroll
  for (int i = 0; i < 13; ++i){
    int idx = gj*13 + i;
    st_r[i] = (idx < HID) ? ST[idx] : INFINITY;
  }
  __syncthreads();   // meta/thresholds consumed; T scratch region now dead

  // ---------- init P2: wave0 table build; waves 1-7 eps generation ----------
  uint32_t A1k = 0u, B1k = 0u;   // kloop key (fallback wave7 only)
  if (wv == 0){
    const int L = lane;          // columns n=L and n=64+L (L<36)
    float a10 = b2[L], a20 = 0.0f;
    float a11 = (L < 36) ? b2[64+L] : 0.0f, a21 = 0.0f;
    // pass 1: rank-0 base = b2 + sum over neg-type features of (+u,+v)*W2row
#pragma unroll 8
    for (int rr = 0; rr < 64; ++rr){
      int   kp = __builtin_amdgcn_readlane(kpA, rr);
      float cu = __int_as_float(__builtin_amdgcn_readlane(__float_as_int(cuA), rr));
      float cv = __int_as_float(__builtin_amdgcn_readlane(__float_as_int(cvA), rr));
      int k = kp & 127;
      float bu = (kp & 128) ? -cu : 0.0f;  // = +u for neg-type, 0 for pos-type
      float bv = (kp & 128) ? -cv : 0.0f;
      float w0 = W2[k*HID + L];
      a10 = fmaf(bu, w0, a10); a20 = fmaf(bv, w0, a20);
      if (L < 36){
        float w1 = W2[k*HID + 64+L];
        a11 = fmaf(bu, w1, a11); a21 = fmaf(bv, w1, a21);
      }
    }
#pragma unroll 6
    for (int rr = 0; rr < 36; ++rr){
      int   kp = __builtin_amdgcn_readlane(kpB, rr);
      float cu = __int_as_float(__builtin_amdgcn_readlane(__float_as_int(cuB), rr));
      float cv = __int_as_float(__builtin_amdgcn_readlane(__float_as_int(cvB), rr));
      int k = kp & 127;
      float bu = (kp & 128) ? -cu : 0.0f;
      float bv = (kp & 128) ? -cv : 0.0f;
      float w0 = W2[k*HID + L];
      a10 = fmaf(bu, w0, a10); a20 = fmaf(bv, w0, a20);
      if (L < 36){
        float w1 = W2[k*HID + 64+L];
        a11 = fmaf(bu, w1, a11); a21 = fmaf(bv, w1, a21);
      }
    }
    { float2 f; f.x = a10; f.y = a20; T2D[L] = f; }
    if (L < 36){ float2 f; f.x = a11; f.y = a21; T2D[64+L] = f; }
    // pass 2: ascending ranks, signed deltas, write T[rr+1]
#pragma unroll 8
    for (int rr = 0; rr < 64; ++rr){
      int   kp = __builtin_amdgcn_readlane(kpA, rr);
      float cu = __int_as_float(__builtin_amdgcn_readlane(__float_as_int(cuA), rr));
      float cv = __int_as_float(__builtin_amdgcn_readlane(__float_as_int(cvA), rr));
      int k = kp & 127;
      float w0 = W2[k*HID + L];
      a10 = fmaf(cu, w0, a10); a20 = fmaf(cv, w0, a20);
      { float2 f; f.x = a10; f.y = a20; T2D[(rr+1)*HID + L] = f; }
      if (L < 36){
        float w1 = W2[k*HID + 64+L];
        a11 = fmaf(cu, w1, a11); a21 = fmaf(cv, w1, a21);
        float2 f; f.x = a11; f.y = a21; T2D[(rr+1)*HID + 64+L] = f;
      }
    }
#pragma unroll 6
    for (int rr = 0; rr < 36; ++rr){
      int   kp = __builtin_amdgcn_readlane(kpB, rr);
      float cu = __int_as_float(__builtin_amdgcn_readlane(__float_as_int(cuB), rr));
      float cv = __int_as_float(__builtin_amdgcn_readlane(__float_as_int(cvB), rr));
      int k = kp & 127;
      float w0 = W2[k*HID + L];
      a10 = fmaf(cu, w0, a10); a20 = fmaf(cv, w0, a20);
      { float2 f; f.x = a10; f.y = a20; T2D[(65+rr)*HID + L] = f; }
      if (L < 36){
        float w1 = W2[k*HID + 64+L];
        a11 = fmaf(cu, w1, a11); a21 = fmaf(cv, w1, a21);
        float2 f; f.x = a11; f.y = a21; T2D[(65+rr)*HID + 64+L] = f;
      }
    }
  } else if (EPSG){
    // ---- waves 1-7: generate this block's eps tensor into d_ws ([b][t][c]) ----
    uint32_t A0c, B0c, A1c, B1c;
    tf2x32(0u,42u,0u,2u,A0c,A1c);      // key(42) split halves
    tf2x32(0u,42u,1u,3u,B0c,B1c);
    if (wv == 1 && lane < MCAND){
      // iteration-0 uniform angles (mu=0, std=1)
      uint32_t gidx = (uint32_t)b*MCAND + (uint32_t)lane;
      uint32_t r0,r1,bits;
      if (gidx < 102400u){ tf2x32(A0c,B0c,gidx,gidx+102400u,r0,r1); bits = r0; }
      else               { tf2x32(A0c,B0c,gidx-102400u,gidx,r0,r1); bits = r1; }
      A[lane] = __uint_as_float((bits>>9) | 0x3f800000u) - 1.0f;
    }
    const int idx0 = tid - 64;          // 0..447
    const int tt   = idx0 >> 2;         // 4 threads per eps row
    if (tt < EPS_ROWS){
      const int c0  = (idx0 & 3) * 13;
      const int cnt = (c0 == 39) ? 11 : 13;
      uint32_t kk0, kk1;                // keys[tt] = (concat[2tt], concat[2tt+1])
      { uint32_t mi = 2u*(uint32_t)tt;      uint32_t ii = (mi < 99u) ? mi : (mi - 99u);
        uint32_t x,y; tf2x32(A1c,B1c, ii, 99u+ii, x, y); kk0 = (mi < 99u) ? x : y; }
      { uint32_t mi = 2u*(uint32_t)tt + 1u; uint32_t ii = (mi < 99u) ? mi : (mi - 99u);
        uint32_t x,y; tf2x32(A1c,B1c, ii, 99u+ii, x, y); kk1 = (mi < 99u) ? x : y; }
      float* Eb = epsg + (size_t)b*EPS_BLK + (size_t)tt*MCAND;
      for (int c = c0; c < c0+cnt; ++c){
        uint32_t gidx = (uint32_t)b*MCAND + (uint32_t)c;
        uint32_t r0,r1,bits;
        if (gidx < 102400u){ tf2x32(kk0,kk1,gidx,gidx+102400u,r0,r1); bits = r0; }
        else               { tf2x32(kk0,kk1,gidx-102400u,gidx,r0,r1); bits = r1; }
        float fl = __uint_as_float((bits>>9) | 0x3f800000u) - 1.0f;
        float u  = fmaxf(MINVC, fl*2.0f + MINVC);
        Eb[c] = SQRT2C * erfinv32(u);
      }
    }
  } else if (wv == 7){
    // ---- fallback init: angles0 + kloop key in regs (in-loop RNG) ----
    uint32_t A0c, B0c, a1t, b1t;
    tf2x32(0u,42u,0u,2u,A0c,a1t);
    tf2x32(0u,42u,1u,3u,B0c,b1t);
    A1k = a1t; B1k = b1t;
    if (lane < MCAND){
      uint32_t gidx = (uint32_t)b*MCAND + (uint32_t)lane;
      uint32_t r0,r1,bits;
      if (gidx < 102400u){ tf2x32(A0c,B0c,gidx,gidx+102400u,r0,r1); bits = r0; }
      else               { tf2x32(A0c,B0c,gidx-102400u,gidx,r0,r1); bits = r1; }
      A[lane] = __uint_as_float((bits>>9) | 0x3f800000u) - 1.0f;
    }
  }
  __syncthreads();   // table + angles0 + eps tensor all visible

  // ---------- CEM loop: 99 evaluations ----------
  int tm3 = 0;       // t % 3 (batch window phase)
#pragma unroll 1
  for (int t = 0; t < 99; ++t){
    // --- wave7: stage 3 eps rows (t..t+2) once per window (L2-hot loads) ---
    if (EPSG && wv == 7 && tm3 == 0 && t < EPS_ROWS){
      const float* Eb = epsg + (size_t)b*EPS_BLK + (size_t)t*MCAND;
      const int lim = EPS_BLK - t*MCAND;   // elems remaining (masks row 98)
#pragma unroll
      for (int j = 0; j < 3; ++j){
        int idx = j*64 + lane;
        if (idx < 150 && idx < lim) EPB[idx] = Eb[idx];
      }
    }
    // --- G: q_c = sum_n relu(T1[r][n] + a*T2[r][n]) * W3[n] ---
    if (gact){
      const float av = A[gc];             // LDS broadcast (8 lanes same addr)
      int rk = 0;
#pragma unroll
      for (int i = 0; i < 13; ++i) rk += (st_r[i] < av) ? 1 : 0;
      rk += DPPI(rk, 0xB1);
      rk += DPPI(rk, 0x4E);
      rk += iswap4(rk);
      const float4* __restrict__ Trow4 = (const float4*)(T2D + rk*HID);
      float acc = 0.0f;
#pragma unroll
      for (int i = 0; i < 7; ++i){
        int p = gj + (i<<3);
        p = (p < MCAND) ? p : (MCAND-1);  // clamp (w3=0 on invalid slots)
        float4 tv = Trow4[p];             // (T1[2p],T2[2p],T1[2p+1],T2[2p+1])
        float h0 = fmaxf(fmaf(av, tv.y, tv.x), 0.0f);
        float h1 = fmaxf(fmaf(av, tv.w, tv.z), 0.0f);
        acc = fmaf(h0, w3a[i], acc);
        acc = fmaf(h1, w3b[i], acc);
      }
      acc = DPPADD(acc, 0xB1);
      acc = DPPADD(acc, 0x4E);
      acc += fswap4(acc);
      if (gj == 0) QB[gc] = acc;
    }
    // --- fallback: per-iter eps on wave 7 ---
    if (!EPSG && wv == 7 && t < EPS_ROWS){
      uint32_t kk0, kk1;
      { uint32_t i0 = 2u*(uint32_t)t; uint32_t ii = (i0 < 99u) ? i0 : (i0 - 99u);
        uint32_t x, y; tf2x32(A1k,B1k, ii, 99u+ii, x, y); kk0 = (i0 < 99u) ? x : y; }
      { uint32_t i1 = 2u*(uint32_t)t + 1u; uint32_t ii = (i1 < 99u) ? i1 : (i1 - 99u);
        uint32_t x, y; tf2x32(A1k,B1k, ii, 99u+ii, x, y); kk1 = (i1 < 99u) ? x : y; }
      if (lane < MCAND){
        uint32_t gidx = (uint32_t)b*MCAND + (uint32_t)lane;
        uint32_t r0, r1, bits;
        if (gidx < 102400u){ tf2x32(kk0,kk1,gidx,gidx+102400u,r0,r1); bits = r0; }
        else               { tf2x32(kk0,kk1,gidx-102400u,gidx,r0,r1); bits = r1; }
        float fl = __uint_as_float((bits>>9) | 0x3f800000u) - 1.0f;
        float u  = fmaxf(MINVC, fl*2.0f + MINVC);
        EPB[lane] = SQRT2C * erfinv32(u);
      }
    }
    __syncthreads();   // B1: q(t) + staged eps visible

    // --- S: wave 0 only — top-32 stats (VALU bitonic), write a(t+1) ---
    if (wv == 0){
      float q = (lane < MCAND) ? (QB[lane] + sB3v) : -INFINITY;
      // sort 32-halves in opposite directions, j=32 max-merge -> top-32 multiset
      float v = q;
#define BST(KK, JJ, PV) { float pv = (PV); bool lower = (lane & (JJ)) == 0; \
        bool asc = (lane & (KK)) != 0; float mn = fminf(v, pv), mx = fmaxf(v, pv); \
        v = (lower == asc) ? mn : mx; }
      BST(2, 1,  DPPF(v, 0xB1))
      BST(4, 2,  DPPF(v, 0x4E))
      BST(4, 1,  DPPF(v, 0xB1))
      BST(8, 4,  fswap4(v))
      BST(8, 2,  DPPF(v, 0x4E))
      BST(8, 1,  DPPF(v, 0xB1))
      BST(16, 8, fswap8(v))
      BST(16, 4, fswap4(v))
      BST(16, 2, DPPF(v, 0x4E))
      BST(16, 1, DPPF(v, 0xB1))
      BST(32, 16, fswap16(v))
      BST(32, 8,  fswap8(v))
      BST(32, 4,  fswap4(v))
      BST(32, 2,  DPPF(v, 0x4E))
      BST(32, 1,  DPPF(v, 0xB1))
#undef BST
      {
        float pv = fswap32(v);
        v = ((lane & 32) == 0) ? fmaxf(v, pv) : fminf(v, pv);
      }
      // sum / sum-of-squares over lanes 0..31 (same add order as before)
      float sv = (lane < NTOP) ? v : 0.0f;
      sv += fswap32(sv);
      sv += fswap16(sv);
      sv += fswap8(sv);
      sv += fswap4(sv);
      sv = DPPADD(sv, 0x4E);
      sv = DPPADD(sv, 0xB1);
      float mun = sv / 32.0f;
      float dv = (lane < NTOP) ? (v - mun) : 0.0f;
      float s2 = dv*dv;
      s2 += fswap32(s2);
      s2 += fswap16(s2);
      s2 += fswap8(s2);
      s2 += fswap4(s2);
      s2 = DPPADD(s2, 0x4E);
      s2 = DPPADD(s2, 0xB1);
      float stdv = sqrtf(s2 / 31.0f);
      if (t == 98){
        if (lane == 0) out[b] = mun * 6.2831854820251465f;  // fp32(2*pi)
      } else if (lane < MCAND){
        float e = EPSG ? EPB[tm3*MCAND + lane] : EPB[lane];
        A[lane] = fmaf(stdv, e, mun);                       // a(t+1)
      }
    }
    __syncthreads();   // B2: a(t+1) visible; QB/EPB slots free for reuse
    tm3 = (tm3 == 2) ? 0 : tm3 + 1;
  }
}

extern "C" void kernel_launch(void* const* d_in, const int* in_sizes, int n_in,
                              void* d_out, int out_size, void* d_ws, size_t ws_size,
                              hipStream_t stream) {
  const float* states = (const float*)d_in[0];
  const float* W1     = (const float*)d_in[1];
  const float* b1     = (const float*)d_in[2];
  const float* W2     = (const float*)d_in[3];
  const float* b2     = (const float*)d_in[4];
  const float* W3     = (const float*)d_in[5];
  const float* b3     = (const float*)d_in[6];
  float* out = (float*)d_out;

  if (d_ws != nullptr && ws_size >= WS_NEED){
    hipLaunchKernelGGL(HIP_KERNEL_NAME(cem_kernel<true>), dim3(BATCH), dim3(512), 0, stream,
                       states, W1, b1, W2, b2, W3, b3, (float*)d_ws, out);
  } else {
    hipLaunchKernelGGL(HIP_KERNEL_NAME(cem_kernel<false>), dim3(BATCH), dim3(512), 0, stream,
                       states, W1, b1, W2, b2, W3, b3, (float*)nullptr, out);
  }
}